// Round 3
// baseline (835.075 us; speedup 1.0000x reference)
//
#include <hip/hip_runtime.h>

constexpr int IND = 128;
constexpr int HD  = 96;
constexpr int OD  = 64;
constexpr int NL  = 4;

struct F3 { float x, y, z; };

__global__ __launch_bounds__(256) void k_hist(const int* __restrict__ dst, int* __restrict__ deg, int E) {
    int e = blockIdx.x * 256 + threadIdx.x;
    if (e < E) atomicAdd(&deg[dst[e]], 1);
}

__global__ __launch_bounds__(256) void k_scan1(const int* __restrict__ deg, int* __restrict__ bsum, int n) {
    int tid = threadIdx.x;
    int base = blockIdx.x * 1024 + tid * 4;
    int s = 0;
    #pragma unroll
    for (int q = 0; q < 4; ++q) { int i = base + q; if (i < n) s += deg[i]; }
    #pragma unroll
    for (int o = 32; o > 0; o >>= 1) s += __shfl_xor(s, o);
    __shared__ int wsum[4];
    int lane = tid & 63, wid = tid >> 6;
    if (lane == 0) wsum[wid] = s;
    __syncthreads();
    if (tid == 0) bsum[blockIdx.x] = wsum[0] + wsum[1] + wsum[2] + wsum[3];
}

__global__ void k_scan2(const int* __restrict__ bsum, int* __restrict__ boff, int nb,
                        int* __restrict__ row_ptr, int n, int E) {
    int l = threadIdx.x;
    int v = (l < nb) ? bsum[l] : 0;
    int incl = v;
    #pragma unroll
    for (int o = 1; o < 64; o <<= 1) { int t = __shfl_up(incl, o); if (l >= o) incl += t; }
    if (l < nb) boff[l] = incl - v;
    if (l == 0) row_ptr[n] = E;
}

__global__ __launch_bounds__(256) void k_scan3(const int* __restrict__ deg, const int* __restrict__ boff,
                                               int* __restrict__ row_ptr, int n) {
    int tid = threadIdx.x;
    int base = blockIdx.x * 1024 + tid * 4;
    int d[4];
    #pragma unroll
    for (int q = 0; q < 4; ++q) { int i = base + q; d[q] = (i < n) ? deg[i] : 0; }
    int tsum = d[0] + d[1] + d[2] + d[3];
    int incl = tsum;
    #pragma unroll
    for (int o = 1; o < 64; o <<= 1) { int t = __shfl_up(incl, o); if ((tid & 63) >= o) incl += t; }
    __shared__ int wsum[4];
    int lane = tid & 63, wid = tid >> 6;
    if (lane == 63) wsum[wid] = incl;
    __syncthreads();
    int woff = 0;
    for (int w = 0; w < wid; ++w) woff += wsum[w];
    int run = boff[blockIdx.x] + woff + (incl - tsum);
    #pragma unroll
    for (int q = 0; q < 4; ++q) {
        int i = base + q;
        if (i < n) { row_ptr[i] = run; run += d[q]; }
    }
}

// fill CSR: srcp[slot] = src[e]; ewp[l][slot] = (ew[l][0][e], ew[l][1][e])
__global__ __launch_bounds__(256) void k_fill(const int* __restrict__ src, const int* __restrict__ dst,
                                              const int* __restrict__ row_ptr, int* __restrict__ cursor,
                                              const float* __restrict__ convE,
                                              int* __restrict__ srcp, float2* __restrict__ ewp, int E) {
    int e = blockIdx.x * 256 + threadIdx.x;
    if (e >= E) return;
    int d = dst[e];
    int pos = atomicAdd(&cursor[d], 1);
    int slot = row_ptr[d] + pos;
    srcp[slot] = src[e];
    #pragma unroll
    for (int l = 0; l < NL; ++l) {
        float2 w;
        w.x = convE[(size_t)(2 * l)     * E + e];
        w.y = convE[(size_t)(2 * l + 1) * E + e];
        ewp[(size_t)l * E + slot] = w;
    }
}

// Fused layer: agg (gather into LDS) + dual-head GEMM + relu.
// 64 nodes/block, 256 threads. LDS 51.2KB -> 3 blocks/CU.
// NOTE: hin and hout MUST be distinct buffers (gather reads arbitrary rows
// cross-block; in-place update races — caused round-2 failure).
constexpr int BR = 64;
constexpr int PIT = HD + 4;   // 100

__global__ __launch_bounds__(256) void k_layer(const float* __restrict__ hin,
                                               const int* __restrict__ row_ptr,
                                               const int* __restrict__ srcp,
                                               const float2* __restrict__ ewp,
                                               const float* __restrict__ W,   // [2][96][96]
                                               float* __restrict__ hout, int n) {
    __shared__ float sA0[BR][PIT];
    __shared__ float sA1[BR][PIT];
    int tid = threadIdx.x;
    int brow = blockIdx.x * BR;

    // ---- phase 1: aggregate this block's 64 rows into LDS ----
    {
        int grp = tid >> 5;          // 0..7
        int lane = tid & 31;
        int off = lane * 3;          // 3 floats per lane
        for (int q = 0; q < 8; ++q) {
            int r = grp * 8 + q;
            int g = brow + r;
            float a0x = 0.f, a0y = 0.f, a0z = 0.f;
            float a1x = 0.f, a1y = 0.f, a1z = 0.f;
            if (g < n) {
                int i = row_ptr[g], end = row_ptr[g + 1];
                for (; i + 2 <= end; i += 2) {
                    int s0 = srcp[i];
                    int s1 = srcp[i + 1];
                    float2 w0 = ewp[i];
                    float2 w1 = ewp[i + 1];
                    F3 v0 = *(const F3*)(hin + (size_t)s0 * HD + off);
                    F3 v1 = *(const F3*)(hin + (size_t)s1 * HD + off);
                    a0x = fmaf(w0.x, v0.x, a0x); a0y = fmaf(w0.x, v0.y, a0y); a0z = fmaf(w0.x, v0.z, a0z);
                    a1x = fmaf(w0.y, v0.x, a1x); a1y = fmaf(w0.y, v0.y, a1y); a1z = fmaf(w0.y, v0.z, a1z);
                    a0x = fmaf(w1.x, v1.x, a0x); a0y = fmaf(w1.x, v1.y, a0y); a0z = fmaf(w1.x, v1.z, a0z);
                    a1x = fmaf(w1.y, v1.x, a1x); a1y = fmaf(w1.y, v1.y, a1y); a1z = fmaf(w1.y, v1.z, a1z);
                }
                if (i < end) {
                    int s0 = srcp[i];
                    float2 w0 = ewp[i];
                    F3 v0 = *(const F3*)(hin + (size_t)s0 * HD + off);
                    a0x = fmaf(w0.x, v0.x, a0x); a0y = fmaf(w0.x, v0.y, a0y); a0z = fmaf(w0.x, v0.z, a0z);
                    a1x = fmaf(w0.y, v0.x, a1x); a1y = fmaf(w0.y, v0.y, a1y); a1z = fmaf(w0.y, v0.z, a1z);
                }
            }
            sA0[r][off] = a0x; sA0[r][off + 1] = a0y; sA0[r][off + 2] = a0z;
            sA1[r][off] = a1x; sA1[r][off + 1] = a1y; sA1[r][off + 2] = a1z;
        }
    }
    __syncthreads();

    // ---- phase 2: h = relu(A0@W0 + A1@W1), W from global (L2-hot) ----
    int tx = tid & 31;               // cols 3tx..3tx+2
    int ty = tid >> 5;               // rows 8ty..8ty+7
    float acc[8][3];
    #pragma unroll
    for (int r = 0; r < 8; ++r) { acc[r][0] = 0.f; acc[r][1] = 0.f; acc[r][2] = 0.f; }

    #pragma unroll
    for (int head = 0; head < 2; ++head) {
        const float* Wh = W + (size_t)head * HD * HD;
        const float (*sAh)[PIT] = head ? sA1 : sA0;
        #pragma unroll 4
        for (int kk = 0; kk < HD; ++kk) {
            F3 wv = *(const F3*)(Wh + (size_t)kk * HD + 3 * tx);
            float a[8];
            #pragma unroll
            for (int r = 0; r < 8; ++r) a[r] = sAh[8 * ty + r][kk];
            #pragma unroll
            for (int r = 0; r < 8; ++r) {
                acc[r][0] = fmaf(a[r], wv.x, acc[r][0]);
                acc[r][1] = fmaf(a[r], wv.y, acc[r][1]);
                acc[r][2] = fmaf(a[r], wv.z, acc[r][2]);
            }
        }
    }
    #pragma unroll
    for (int r = 0; r < 8; ++r) {
        int gr = brow + 8 * ty + r;
        if (gr < n) {
            float* op = hout + (size_t)gr * HD + 3 * tx;
            op[0] = fmaxf(acc[r][0], 0.f);
            op[1] = fmaxf(acc[r][1], 0.f);
            op[2] = fmaxf(acc[r][2], 0.f);
        }
    }
}

// Encoder/decoder GEMM: 64 rows/block, 256 threads, full-K A staged in LDS, W from global.
template<int K, int NO, bool RELU>
__global__ __launch_bounds__(256) void k_mlp(const float* __restrict__ A,
                                             const float* __restrict__ W,
                                             const float* __restrict__ bias,
                                             float* __restrict__ out, int n) {
    constexpr int P = K + 4;
    constexpr int NC = NO / 32;
    __shared__ float sA[64][P];
    int tid = threadIdx.x;
    int brow = blockIdx.x * 64;
    constexpr int F4 = K / 4;
    for (int i = tid; i < 64 * F4; i += 256) {
        int r = i / F4, c4 = i % F4;
        int gr = brow + r;
        float4 v = make_float4(0.f, 0.f, 0.f, 0.f);
        if (gr < n) v = *(const float4*)(A + (size_t)gr * K + 4 * c4);
        *(float4*)&sA[r][4 * c4] = v;
    }
    __syncthreads();
    int tx = tid & 31;
    int ty = tid >> 5;
    float acc[8][NC];
    #pragma unroll
    for (int r = 0; r < 8; ++r)
        #pragma unroll
        for (int j = 0; j < NC; ++j) acc[r][j] = 0.f;
    #pragma unroll 4
    for (int kk = 0; kk < K; ++kk) {
        float wv[NC];
        #pragma unroll
        for (int j = 0; j < NC; ++j) wv[j] = W[(size_t)kk * NO + NC * tx + j];
        float a[8];
        #pragma unroll
        for (int r = 0; r < 8; ++r) a[r] = sA[8 * ty + r][kk];
        #pragma unroll
        for (int r = 0; r < 8; ++r)
            #pragma unroll
            for (int j = 0; j < NC; ++j) acc[r][j] = fmaf(a[r], wv[j], acc[r][j]);
    }
    #pragma unroll
    for (int r = 0; r < 8; ++r) {
        int gr = brow + 8 * ty + r;
        if (gr < n) {
            float* op = out + (size_t)gr * NO + NC * tx;
            #pragma unroll
            for (int j = 0; j < NC; ++j) {
                float v = acc[r][j] + bias[NC * tx + j];
                if (RELU) v = fmaxf(v, 0.f);
                op[j] = v;
            }
        }
    }
}

extern "C" void kernel_launch(void* const* d_in, const int* in_sizes, int n_in,
                              void* d_out, int out_size, void* d_ws, size_t ws_size,
                              hipStream_t stream) {
    const float* x     = (const float*)d_in[0];
    const int*   ei    = (const int*)  d_in[1];
    const float* enc_w = (const float*)d_in[2];
    const float* enc_b = (const float*)d_in[3];
    const float* dec_w = (const float*)d_in[4];
    const float* dec_b = (const float*)d_in[5];
    const float* convW = (const float*)d_in[6];
    const float* convE = (const float*)d_in[7];

    const int N = in_sizes[0] / IND;
    const int E = in_sizes[1] / 2;
    const int* src = ei;
    const int* dst = ei + E;
    float* fout = (float*)d_out;

    char* wp = (char*)d_ws;
    auto carve = [&](size_t bytes) -> void* {
        void* p = (void*)wp;
        wp += (bytes + 255) & ~(size_t)255;
        return p;
    };
    int*    deg     = (int*)carve(2 * (size_t)N * 4);   // deg | cursor (one memset)
    int*    cursor  = deg + N;
    int*    row_ptr = (int*)carve(((size_t)N + 1) * 4);
    int*    bsum    = (int*)carve(64 * 4);
    int*    boff    = (int*)carve(64 * 4);
    int*    srcp    = (int*)carve((size_t)E * 4);
    float2* ewp     = (float2*)carve((size_t)NL * E * 8);
    float*  hbuf    = (float*)carve((size_t)N * HD * 4);

    hipMemsetAsync(deg, 0, 2 * (size_t)N * 4, stream);

    int ebl = (E + 255) / 256;
    int nb  = (N + 1023) / 1024;
    k_hist<<<ebl, 256, 0, stream>>>(dst, deg, E);
    k_scan1<<<nb, 256, 0, stream>>>(deg, bsum, N);
    k_scan2<<<1, 64, 0, stream>>>(bsum, boff, nb, row_ptr, N, E);
    k_scan3<<<nb, 256, 0, stream>>>(deg, boff, row_ptr, N);
    k_fill<<<ebl, 256, 0, stream>>>(src, dst, row_ptr, cursor, convE, srcp, ewp, E);

    int gbl = (N + 63) / 64;
    float* hfin = fout + (size_t)N * OD;   // output-1 region doubles as h ping-pong slot

    // ping-pong: enc->hfin; L0: hfin->hbuf; L1: hbuf->hfin; L2: hfin->hbuf; L3: hbuf->hfin
    k_mlp<IND, HD, true><<<gbl, 256, 0, stream>>>(x, enc_w, enc_b, hfin, N);

    float* bufs[2] = { hfin, hbuf };
    for (int l = 0; l < NL; ++l) {
        const float* Wl = convW + (size_t)l * 2 * HD * HD;
        const float* hi = bufs[l & 1];
        float*       ho = bufs[(l + 1) & 1];
        k_layer<<<gbl, 256, 0, stream>>>(hi, row_ptr, srcp, ewp + (size_t)l * E, Wl, ho, N);
    }
    // NL even -> final h is in hfin (= fout + N*OD), exactly output 1.
    k_mlp<HD, OD, false><<<gbl, 256, 0, stream>>>(hfin, dec_w, dec_b, fout, N);
}

// Round 4
// 687.332 us; speedup vs baseline: 1.2150x; 1.2150x over previous
//
#include <hip/hip_runtime.h>

constexpr int IND = 128;
constexpr int HD  = 96;
constexpr int OD  = 64;
constexpr int NL  = 4;

struct F3 { float x, y, z; };

__global__ __launch_bounds__(256) void k_hist(const int* __restrict__ dst, int* __restrict__ deg, int E) {
    int e = blockIdx.x * 256 + threadIdx.x;
    if (e < E) atomicAdd(&deg[dst[e]], 1);
}

__global__ __launch_bounds__(256) void k_scan1(const int* __restrict__ deg, int* __restrict__ bsum, int n) {
    int tid = threadIdx.x;
    int base = blockIdx.x * 1024 + tid * 4;
    int s = 0;
    #pragma unroll
    for (int q = 0; q < 4; ++q) { int i = base + q; if (i < n) s += deg[i]; }
    #pragma unroll
    for (int o = 32; o > 0; o >>= 1) s += __shfl_xor(s, o);
    __shared__ int wsum[4];
    int lane = tid & 63, wid = tid >> 6;
    if (lane == 0) wsum[wid] = s;
    __syncthreads();
    if (tid == 0) bsum[blockIdx.x] = wsum[0] + wsum[1] + wsum[2] + wsum[3];
}

__global__ void k_scan2(const int* __restrict__ bsum, int* __restrict__ boff, int nb,
                        int* __restrict__ row_ptr, int n, int E) {
    int l = threadIdx.x;
    int v = (l < nb) ? bsum[l] : 0;
    int incl = v;
    #pragma unroll
    for (int o = 1; o < 64; o <<= 1) { int t = __shfl_up(incl, o); if (l >= o) incl += t; }
    if (l < nb) boff[l] = incl - v;
    if (l == 0) row_ptr[n] = E;
}

__global__ __launch_bounds__(256) void k_scan3(const int* __restrict__ deg, const int* __restrict__ boff,
                                               int* __restrict__ row_ptr, int n) {
    int tid = threadIdx.x;
    int base = blockIdx.x * 1024 + tid * 4;
    int d[4];
    #pragma unroll
    for (int q = 0; q < 4; ++q) { int i = base + q; d[q] = (i < n) ? deg[i] : 0; }
    int tsum = d[0] + d[1] + d[2] + d[3];
    int incl = tsum;
    #pragma unroll
    for (int o = 1; o < 64; o <<= 1) { int t = __shfl_up(incl, o); if ((tid & 63) >= o) incl += t; }
    __shared__ int wsum[4];
    int lane = tid & 63, wid = tid >> 6;
    if (lane == 63) wsum[wid] = incl;
    __syncthreads();
    int woff = 0;
    for (int w = 0; w < wid; ++w) woff += wsum[w];
    int run = boff[blockIdx.x] + woff + (incl - tsum);
    #pragma unroll
    for (int q = 0; q < 4; ++q) {
        int i = base + q;
        if (i < n) { row_ptr[i] = run; run += d[q]; }
    }
}

// fill CSR: srcp[slot] = src[e]; ewp[l][slot] = (ew[l][0][e], ew[l][1][e])
__global__ __launch_bounds__(256) void k_fill(const int* __restrict__ src, const int* __restrict__ dst,
                                              const int* __restrict__ row_ptr, int* __restrict__ cursor,
                                              const float* __restrict__ convE,
                                              int* __restrict__ srcp, float2* __restrict__ ewp, int E) {
    int e = blockIdx.x * 256 + threadIdx.x;
    if (e >= E) return;
    int d = dst[e];
    int pos = atomicAdd(&cursor[d], 1);
    int slot = row_ptr[d] + pos;
    srcp[slot] = src[e];
    #pragma unroll
    for (int l = 0; l < NL; ++l) {
        float2 w;
        w.x = convE[(size_t)(2 * l)     * E + e];
        w.y = convE[(size_t)(2 * l + 1) * E + e];
        ewp[(size_t)l * E + slot] = w;
    }
}

// Fused layer: agg (gather into LDS) + dual-head GEMM + relu.
// BR=32 nodes/block, 256 threads. LDS 24.6KB -> 6 blocks/CU = 24 waves (75% occ);
// round-3's BR=64 (51.2KB, 3 blocks/CU, 19% occ) starved the latency-bound gather.
// NOTE: hin and hout MUST be distinct buffers (gather reads arbitrary rows
// cross-block; in-place update races — caused round-2 failure).
constexpr int BR = 32;

__global__ __launch_bounds__(256) void k_layer(const float* __restrict__ hin,
                                               const int* __restrict__ row_ptr,
                                               const int* __restrict__ srcp,
                                               const float2* __restrict__ ewp,
                                               const float* __restrict__ W,   // [2][96][96]
                                               float* __restrict__ hout, int n) {
    __shared__ float sA0[BR][HD];   // bank-conflict-free: writes stride 3 (gcd(3,32)=1),
    __shared__ float sA1[BR][HD];   // reads are half-wave broadcasts; row stride 96%32==0 -> free 2-way
    int tid = threadIdx.x;
    int brow = blockIdx.x * BR;

    // ---- phase 1: aggregate this block's 32 rows into LDS ----
    {
        int grp = tid >> 5;          // 0..7, 4 rows each
        int lane = tid & 31;
        int off = lane * 3;          // 3 floats per lane
        for (int q = 0; q < 4; ++q) {
            int r = grp * 4 + q;
            int g = brow + r;
            float a0x = 0.f, a0y = 0.f, a0z = 0.f;
            float a1x = 0.f, a1y = 0.f, a1z = 0.f;
            if (g < n) {
                int i = row_ptr[g], end = row_ptr[g + 1];
                for (; i + 2 <= end; i += 2) {
                    int s0 = srcp[i];
                    int s1 = srcp[i + 1];
                    float2 w0 = ewp[i];
                    float2 w1 = ewp[i + 1];
                    F3 v0 = *(const F3*)(hin + (size_t)s0 * HD + off);
                    F3 v1 = *(const F3*)(hin + (size_t)s1 * HD + off);
                    a0x = fmaf(w0.x, v0.x, a0x); a0y = fmaf(w0.x, v0.y, a0y); a0z = fmaf(w0.x, v0.z, a0z);
                    a1x = fmaf(w0.y, v0.x, a1x); a1y = fmaf(w0.y, v0.y, a1y); a1z = fmaf(w0.y, v0.z, a1z);
                    a0x = fmaf(w1.x, v1.x, a0x); a0y = fmaf(w1.x, v1.y, a0y); a0z = fmaf(w1.x, v1.z, a0z);
                    a1x = fmaf(w1.y, v1.x, a1x); a1y = fmaf(w1.y, v1.y, a1y); a1z = fmaf(w1.y, v1.z, a1z);
                }
                if (i < end) {
                    int s0 = srcp[i];
                    float2 w0 = ewp[i];
                    F3 v0 = *(const F3*)(hin + (size_t)s0 * HD + off);
                    a0x = fmaf(w0.x, v0.x, a0x); a0y = fmaf(w0.x, v0.y, a0y); a0z = fmaf(w0.x, v0.z, a0z);
                    a1x = fmaf(w0.y, v0.x, a1x); a1y = fmaf(w0.y, v0.y, a1y); a1z = fmaf(w0.y, v0.z, a1z);
                }
            }
            sA0[r][off] = a0x; sA0[r][off + 1] = a0y; sA0[r][off + 2] = a0z;
            sA1[r][off] = a1x; sA1[r][off + 1] = a1y; sA1[r][off + 2] = a1z;
        }
    }
    __syncthreads();

    // ---- phase 2: h = relu(A0@W0 + A1@W1), W from global (L2-hot) ----
    int tx = tid & 31;               // cols 3tx..3tx+2
    int ty = tid >> 5;               // rows 4ty..4ty+3
    float acc[4][3];
    #pragma unroll
    for (int r = 0; r < 4; ++r) { acc[r][0] = 0.f; acc[r][1] = 0.f; acc[r][2] = 0.f; }

    #pragma unroll
    for (int head = 0; head < 2; ++head) {
        const float* Wh = W + (size_t)head * HD * HD;
        const float (*sAh)[HD] = head ? sA1 : sA0;
        #pragma unroll 4
        for (int kk = 0; kk < HD; ++kk) {
            F3 wv = *(const F3*)(Wh + (size_t)kk * HD + 3 * tx);
            float a[4];
            #pragma unroll
            for (int r = 0; r < 4; ++r) a[r] = sAh[4 * ty + r][kk];
            #pragma unroll
            for (int r = 0; r < 4; ++r) {
                acc[r][0] = fmaf(a[r], wv.x, acc[r][0]);
                acc[r][1] = fmaf(a[r], wv.y, acc[r][1]);
                acc[r][2] = fmaf(a[r], wv.z, acc[r][2]);
            }
        }
    }
    #pragma unroll
    for (int r = 0; r < 4; ++r) {
        int gr = brow + 4 * ty + r;
        if (gr < n) {
            float* op = hout + (size_t)gr * HD + 3 * tx;
            op[0] = fmaxf(acc[r][0], 0.f);
            op[1] = fmaxf(acc[r][1], 0.f);
            op[2] = fmaxf(acc[r][2], 0.f);
        }
    }
}

// Encoder/decoder GEMM: 64 rows/block, 256 threads, full-K A staged in LDS, W from global.
template<int K, int NO, bool RELU>
__global__ __launch_bounds__(256) void k_mlp(const float* __restrict__ A,
                                             const float* __restrict__ W,
                                             const float* __restrict__ bias,
                                             float* __restrict__ out, int n) {
    constexpr int P = K + 4;
    constexpr int NC = NO / 32;
    __shared__ float sA[64][P];
    int tid = threadIdx.x;
    int brow = blockIdx.x * 64;
    constexpr int F4 = K / 4;
    for (int i = tid; i < 64 * F4; i += 256) {
        int r = i / F4, c4 = i % F4;
        int gr = brow + r;
        float4 v = make_float4(0.f, 0.f, 0.f, 0.f);
        if (gr < n) v = *(const float4*)(A + (size_t)gr * K + 4 * c4);
        *(float4*)&sA[r][4 * c4] = v;
    }
    __syncthreads();
    int tx = tid & 31;
    int ty = tid >> 5;
    float acc[8][NC];
    #pragma unroll
    for (int r = 0; r < 8; ++r)
        #pragma unroll
        for (int j = 0; j < NC; ++j) acc[r][j] = 0.f;
    #pragma unroll 4
    for (int kk = 0; kk < K; ++kk) {
        float wv[NC];
        #pragma unroll
        for (int j = 0; j < NC; ++j) wv[j] = W[(size_t)kk * NO + NC * tx + j];
        float a[8];
        #pragma unroll
        for (int r = 0; r < 8; ++r) a[r] = sA[8 * ty + r][kk];
        #pragma unroll
        for (int r = 0; r < 8; ++r)
            #pragma unroll
            for (int j = 0; j < NC; ++j) acc[r][j] = fmaf(a[r], wv[j], acc[r][j]);
    }
    #pragma unroll
    for (int r = 0; r < 8; ++r) {
        int gr = brow + 8 * ty + r;
        if (gr < n) {
            float* op = out + (size_t)gr * NO + NC * tx;
            #pragma unroll
            for (int j = 0; j < NC; ++j) {
                float v = acc[r][j] + bias[NC * tx + j];
                if (RELU) v = fmaxf(v, 0.f);
                op[j] = v;
            }
        }
    }
}

extern "C" void kernel_launch(void* const* d_in, const int* in_sizes, int n_in,
                              void* d_out, int out_size, void* d_ws, size_t ws_size,
                              hipStream_t stream) {
    const float* x     = (const float*)d_in[0];
    const int*   ei    = (const int*)  d_in[1];
    const float* enc_w = (const float*)d_in[2];
    const float* enc_b = (const float*)d_in[3];
    const float* dec_w = (const float*)d_in[4];
    const float* dec_b = (const float*)d_in[5];
    const float* convW = (const float*)d_in[6];
    const float* convE = (const float*)d_in[7];

    const int N = in_sizes[0] / IND;
    const int E = in_sizes[1] / 2;
    const int* src = ei;
    const int* dst = ei + E;
    float* fout = (float*)d_out;

    char* wp = (char*)d_ws;
    auto carve = [&](size_t bytes) -> void* {
        void* p = (void*)wp;
        wp += (bytes + 255) & ~(size_t)255;
        return p;
    };
    int*    deg     = (int*)carve(2 * (size_t)N * 4);   // deg | cursor (one memset)
    int*    cursor  = deg + N;
    int*    row_ptr = (int*)carve(((size_t)N + 1) * 4);
    int*    bsum    = (int*)carve(64 * 4);
    int*    boff    = (int*)carve(64 * 4);
    int*    srcp    = (int*)carve((size_t)E * 4);
    float2* ewp     = (float2*)carve((size_t)NL * E * 8);
    float*  hbuf    = (float*)carve((size_t)N * HD * 4);

    hipMemsetAsync(deg, 0, 2 * (size_t)N * 4, stream);

    int ebl = (E + 255) / 256;
    int nb  = (N + 1023) / 1024;
    k_hist<<<ebl, 256, 0, stream>>>(dst, deg, E);
    k_scan1<<<nb, 256, 0, stream>>>(deg, bsum, N);
    k_scan2<<<1, 64, 0, stream>>>(bsum, boff, nb, row_ptr, N, E);
    k_scan3<<<nb, 256, 0, stream>>>(deg, boff, row_ptr, N);
    k_fill<<<ebl, 256, 0, stream>>>(src, dst, row_ptr, cursor, convE, srcp, ewp, E);

    int gbl64 = (N + 63) / 64;
    int gbl32 = (N + BR - 1) / BR;
    float* hfin = fout + (size_t)N * OD;   // output-1 region doubles as h ping-pong slot

    // ping-pong: enc->hfin; L0: hfin->hbuf; L1: hbuf->hfin; L2: hfin->hbuf; L3: hbuf->hfin
    k_mlp<IND, HD, true><<<gbl64, 256, 0, stream>>>(x, enc_w, enc_b, hfin, N);

    float* bufs[2] = { hfin, hbuf };
    for (int l = 0; l < NL; ++l) {
        const float* Wl = convW + (size_t)l * 2 * HD * HD;
        const float* hi = bufs[l & 1];
        float*       ho = bufs[(l + 1) & 1];
        k_layer<<<gbl32, 256, 0, stream>>>(hi, row_ptr, srcp, ewp + (size_t)l * E, Wl, ho, N);
    }
    // NL even -> final h is in hfin (= fout + N*OD), exactly output 1.
    k_mlp<HD, OD, false><<<gbl64, 256, 0, stream>>>(hfin, dec_w, dec_b, fout, N);
}